// Round 5
// baseline (146.614 us; speedup 1.0000x reference)
//
#include <hip/hip_runtime.h>
#include <math.h>

constexpr int H_ = 180, W_ = 320, RF_ = 16, K_ = 20, T_ = 400;
constexpr int HW_ = H_ * W_;
constexpr int NWIN = T_ - K_ + 1;   // 381
constexpr int PW   = W_ + 2 * RF_;  // 352 (padded width used by rf_indices)
constexpr float ALPHA = 50.0f, BETA = 1.0f, GAMMA = 0.0f;
constexpr int BSTEP  = 48;          // band step (rows)
constexpr int NBANDS = 4;           // ceil(165/48)
constexpr int BROWS  = 64;          // staged rows per band (48 + 15 halo, padded)

__device__ inline float wave_sum64(float v) {
#pragma unroll
    for (int off = 1; off < 64; off <<= 1)
        v += __shfl_xor(v, off, 64);
    return v;
}

// ---------------------------------------------------------------------------
// prep: (a) threads 0..959: partition neurons into row-bands by clamped
// window-top r0c (atomic per-band lists); (b) wave 15: rank-1 factorization
// of w into temporal[K] (x) spatial[256] (LS-projection on largest row).
// Single block; runs every launch (cnt re-zeroed -> deterministic output).
// ---------------------------------------------------------------------------
__global__ __launch_bounds__(1024) void prep_kernel(
    const float* __restrict__ w, const int* __restrict__ rf,
    float* __restrict__ spatial, float* __restrict__ temporal,
    int* __restrict__ cnt, int* __restrict__ lists, int N)
{
    int tid = threadIdx.x;
    if (tid < NBANDS) cnt[tid] = 0;
    __syncthreads();

    if (tid < 960) {
        for (int n = tid; n < N; n += 960) {
            int base = rf[n * 256];
            int r0   = base / PW - RF_;
            int r0c  = min(max(r0, 0), H_ - RF_);
            int b    = r0c / BSTEP;              // 0..3
            int slot = atomicAdd(&cnt[b], 1);
            lists[b * N + slot] = n;
        }
    } else {
        int l = tid - 960;  // 0..63, one full wave
        float best = -1.0f;
        int k0 = 0;
        for (int k = 0; k < K_; ++k) {
            float s = 0.0f;
#pragma unroll
            for (int j = 0; j < 4; ++j) {
                float v = w[k * 256 + l + j * 64];
                s = fmaf(v, v, s);
            }
            s = wave_sum64(s);
            if (s > best) { best = s; k0 = k; }
        }
#pragma unroll
        for (int j = 0; j < 4; ++j)
            spatial[l + j * 64] = w[k0 * 256 + l + j * 64];
        float inv_s2 = 1.0f / best;
        for (int k = 0; k < K_; ++k) {
            float d = 0.0f;
#pragma unroll
            for (int j = 0; j < 4; ++j)
                d = fmaf(w[k * 256 + l + j * 64], w[k0 * 256 + l + j * 64], d);
            d = wave_sum64(d);
            if (l == 0) temporal[k] = d * inv_s2;
        }
    }
}

// ---------------------------------------------------------------------------
// Stage 1: y[n, t] = sum_p x_patch[t, n, p] * spatial[p]
//
// Block = (frame t, band b). Stage band rows [48b, 48b+64) of frame t into
// 80 KB LDS (2 blocks/CU) with XOR bank-swizzle col' = col ^ (4*(row&7)),
// then every band-neuron reads its 16x16 window via aligned ds_read_b128:
// 16 lanes = 16 window rows, 4 neurons per wave. Mosaic x-positions are
// multiples of 4 -> windows are 16B-aligned (fast path); clamped border
// neurons take a per-element fallback with shifted/masked weights
// (exact zero-pad semantics).
// ---------------------------------------------------------------------------
__global__ __launch_bounds__(256) void stage1_kernel(
    const float* __restrict__ x, const int* __restrict__ rf,
    const float* __restrict__ spatial,
    const int* __restrict__ cnt, const int* __restrict__ lists,
    float* __restrict__ y, int N)
{
    __shared__ float lds[BROWS * W_];   // 80 KB

    int tid = threadIdx.x;
    int b   = blockIdx.x & (NBANDS - 1);
    int t   = blockIdx.x >> 2;
    int band0 = b * BSTEP;
    int rows  = min(BROWS, H_ - band0);
    int words = rows * W_;

    // ---- stage band -> LDS (coalesced float4, swizzled write) ----
    const float* xb = x + (size_t)t * HW_ + band0 * W_;
    for (int wi = tid * 4; wi < words; wi += 1024) {
        float4 v = *reinterpret_cast<const float4*>(xb + wi);
        int row  = wi / W_;
        int col  = wi - row * W_;
        int colp = col ^ ((row & 7) << 2);
        *reinterpret_cast<float4*>(&lds[row * W_ + colp]) = v;
    }

    int lane = tid & 63;
    int wid  = tid >> 6;
    int r    = lane & 15;   // window row handled by this lane
    // preload unshifted weights for row r (fast path)
    float4 wq[4];
#pragma unroll
    for (int q = 0; q < 4; ++q)
        wq[q] = *reinterpret_cast<const float4*>(spatial + r * RF_ + q * 4);

    __syncthreads();

    int count = cnt[b];
    const int* list = lists + b * N;

    for (int i0 = wid * 4 + (lane >> 4); i0 < count; i0 += 16) {
        int n    = list[i0];
        int base = rf[n * 256];
        int v0   = base / PW;
        int r0   = v0 - RF_;
        int c0   = (base - v0 * PW) - RF_;
        int r0c  = min(max(r0, 0), H_ - RF_);
        int c0c  = min(max(c0, 0), W_ - RF_);
        int dr   = r0c - r0;
        int dc   = c0c - c0;
        int lr   = r0c - band0 + r;
        int rowbase = lr * W_;
        int xr      = (lr & 7) << 2;

        float a = 0.0f;
        if (((dr | dc) == 0) & ((c0c & 3) == 0)) {
            // fast path: interior neuron, 16B-aligned window
#pragma unroll
            for (int q = 0; q < 4; ++q) {
                const float4 p = *reinterpret_cast<const float4*>(
                    &lds[rowbase + ((c0c + q * 4) ^ xr)]);
                a = fmaf(p.x, wq[q].x, a);
                a = fmaf(p.y, wq[q].y, a);
                a = fmaf(p.z, wq[q].z, a);
                a = fmaf(p.w, wq[q].w, a);
            }
        } else {
            // border fallback: clamped window + shifted/masked weights
            int rr = r + dr;
            bool rok = (rr >= 0) & (rr < RF_);
#pragma unroll
            for (int j = 0; j < RF_; ++j) {
                int cc = j + dc;
                bool ok = rok & (cc >= 0) & (cc < RF_);
                float wv = 0.0f;
                if (ok) wv = spatial[rr * RF_ + cc];
                float pv = lds[rowbase + ((c0c + j) ^ xr)];
                a = fmaf(pv, wv, a);
            }
        }
        // reduce across the 16 row-lanes
        a += __shfl_xor(a, 1, 64);
        a += __shfl_xor(a, 2, 64);
        a += __shfl_xor(a, 4, 64);
        a += __shfl_xor(a, 8, 64);
        if (r == 0) y[(size_t)n * T_ + t] = a;
    }
}

// ---------------------------------------------------------------------------
// Stage 2: out[n, t0] = ALPHA * softplus(BETA * (sum_k y[n,t0+k]*temporal[k]
//                                                 - GAMMA))
// ---------------------------------------------------------------------------
__global__ void stage2_kernel(const float* __restrict__ y,
                              const float* __restrict__ temporal,
                              float* __restrict__ out, int N)
{
    __shared__ float tw[K_];
    if (threadIdx.x < K_) tw[threadIdx.x] = temporal[threadIdx.x];
    __syncthreads();

    int n  = blockIdx.x;
    int t0 = threadIdx.x;
    if (n >= N || t0 >= NWIN) return;

    const float* yn = y + (size_t)n * T_;
    float g = 0.0f;
#pragma unroll
    for (int k = 0; k < K_; ++k)
        g = fmaf(yn[t0 + k], tw[k], g);

    float z = BETA * (g - GAMMA);
    float sp = fmaxf(z, 0.0f) + log1pf(expf(-fabsf(z)));
    out[n * NWIN + t0] = ALPHA * sp;
}

// ---------------------------------------------------------------------------
extern "C" void kernel_launch(void* const* d_in, const int* in_sizes, int n_in,
                              void* d_out, int out_size, void* d_ws, size_t ws_size,
                              hipStream_t stream)
{
    const float* x  = (const float*)d_in[0];  // (T, H, W) f32
    const float* w  = (const float*)d_in[1];  // (K*RF*RF,) f32
    const int*   rf = (const int*)d_in[2];    // (N, 256) i32

    int N = in_sizes[2] / (RF_ * RF_);

    // ws layout (4B units): [0..255] spatial | [256..319] temporal(pad)
    //                       [320..383] cnt(pad) | [384..384+4N) lists | y
    float* spatial  = (float*)d_ws;
    float* temporal = spatial + 256;
    int*   cnt      = (int*)d_ws + 320;
    int*   lists    = (int*)d_ws + 384;
    float* y        = (float*)d_ws + 384 + 4 * N;

    prep_kernel<<<1, 1024, 0, stream>>>(w, rf, spatial, temporal, cnt, lists, N);
    stage1_kernel<<<T_ * NBANDS, 256, 0, stream>>>(x, rf, spatial, cnt, lists, y, N);
    stage2_kernel<<<N, 384, 0, stream>>>(y, temporal, (float*)d_out, N);
}

// Round 6
// 89.869 us; speedup vs baseline: 1.6314x; 1.6314x over previous
//
#include <hip/hip_runtime.h>
#include <math.h>

constexpr int H_ = 180, W_ = 320, RF_ = 16, K_ = 20, T_ = 400;
constexpr int HW_ = H_ * W_;
constexpr int NWIN = T_ - K_ + 1;   // 381
constexpr int PW   = W_ + 2 * RF_;  // 352 (padded width used by rf_indices)
constexpr float ALPHA = 50.0f, BETA = 1.0f, GAMMA = 0.0f;

constexpr int BSTEP  = 20;          // band step (rows)
constexpr int NBANDS = 9;           // ceil(165/20)
constexpr int BROWS  = 36;          // staged rows (20 + 16 halo)
constexpr int RP     = 324;         // LDS row stride, words (=4 mod 32 -> bank spread)
constexpr int WPR    = 36;          // padded-weight row stride, words
constexpr int WROWS  = 32;          // padded-weight rows (rr in [-8,23])
constexpr int LDSX_W = BROWS * RP;          // 11664 words
constexpr int LDSW_W = WROWS * WPR;         // 1152 words
constexpr int NXCD = 8;
constexpr int FR_PER_XCD = T_ / NXCD;       // 50

__device__ inline float wave_sum64(float v) {
#pragma unroll
    for (int off = 1; off < 64; off <<= 1)
        v += __shfl_xor(v, off, 64);
    return v;
}

// ---------------------------------------------------------------------------
// prep: (a) wave 15 factorizes w (exact rank-1) into spatial[256]+temporal[K];
// (b) threads <960 bucket neurons into 9 row-bands with precomputed LDS
// descriptors {n, xrow, wrow}; (c) after sync, build zero-padded weight
// table spat_pad[32][36] (rows/cols -8..). Single block, runs every launch.
// ---------------------------------------------------------------------------
__global__ __launch_bounds__(1024) void prep_kernel(
    const float* __restrict__ w, const int* __restrict__ rf,
    float* __restrict__ spatial, float* __restrict__ temporal,
    float* __restrict__ spat_pad, int* __restrict__ cnt,
    int4* __restrict__ lists, int N)
{
    int tid = threadIdx.x;
    if (tid < NBANDS) cnt[tid] = 0;
    __syncthreads();

    if (tid >= 960) {
        int l = tid - 960;  // one full wave
        float best = -1.0f;
        int k0 = 0;
        for (int k = 0; k < K_; ++k) {
            float s = 0.0f;
#pragma unroll
            for (int j = 0; j < 4; ++j) {
                float v = w[k * 256 + l + j * 64];
                s = fmaf(v, v, s);
            }
            s = wave_sum64(s);
            if (s > best) { best = s; k0 = k; }
        }
#pragma unroll
        for (int j = 0; j < 4; ++j)
            spatial[l + j * 64] = w[k0 * 256 + l + j * 64];
        float inv_s2 = 1.0f / best;
        for (int k = 0; k < K_; ++k) {
            float d = 0.0f;
#pragma unroll
            for (int j = 0; j < 4; ++j)
                d = fmaf(w[k * 256 + l + j * 64], w[k0 * 256 + l + j * 64], d);
            d = wave_sum64(d);
            if (l == 0) temporal[k] = d * inv_s2;
        }
    } else {
        for (int n = tid; n < N; n += 960) {
            int base = rf[n * 256];
            int v0   = base / PW;
            int r0   = v0 - RF_;
            int c0   = (base - v0 * PW) - RF_;
            int r0c  = min(max(r0, 0), H_ - RF_);
            int c0c  = min(max(c0, 0), W_ - RF_);
            int b    = r0c / BSTEP;              // 0..8
            int slot = atomicAdd(&cnt[b], 1);
            int4 d;
            d.x = n;
            d.y = (r0c - b * BSTEP) * RP + c0c;              // LDS window base
            d.z = (r0c - r0 + 8) * WPR + (c0c - c0 + 8);     // padded-w base
            d.w = 0;
            lists[b * N + slot] = d;
        }
    }
    __syncthreads();
    // padded weight table (reads spatial written by wave 15; same block)
    for (int i = tid; i < LDSW_W; i += 1024) {
        int rr = i / WPR - 8;
        int cc = i % WPR - 8;
        bool ok = (rr >= 0) & (rr < RF_) & (cc >= 0) & (cc < RF_);
        spat_pad[i] = ok ? spatial[rr * RF_ + cc] : 0.0f;
    }
}

// ---------------------------------------------------------------------------
// Stage 1: y[n, t] = sum_p x_patch[t, n, p] * spatial[p]
//
// Block = (frame t, band b), swizzled so XCD k owns frames [50k, 50k+50).
// Stage 36 band rows into LDS at row stride 324 words (=4 mod 32: lane r of
// a 16-lane neuron-group hits bank-group (r+q+c/4)%8 -> exactly the b128
// throughput floor, conflict-free for ANY window position). All neurons take
// ONE uniform path: clamped window reads + shifted zero-padded weight reads,
// both 16B-aligned ds_read_b128 (mosaic x-lattice => c0,dc = 0 mod 4).
// 4 waves x 4 neuron-groups x 16 row-lanes; 4-step shuffle reduce.
// ---------------------------------------------------------------------------
__global__ __launch_bounds__(256) void stage1_kernel(
    const float* __restrict__ x,
    const float* __restrict__ spat_pad,
    const int* __restrict__ cnt, const int4* __restrict__ lists,
    float* __restrict__ y, int N)
{
    __shared__ float lds[LDSX_W + LDSW_W];   // 51.26 KB -> 3 blocks/CU
    float* ldsw = lds + LDSX_W;

    int tid = threadIdx.x;

    // XCD swizzle: xcd = f&7 owns 50 frames; within, bands vary fastest.
    int f   = blockIdx.x;
    int xcd = f & (NXCD - 1);
    int j   = f >> 3;                 // 0..449
    int t   = xcd * FR_PER_XCD + j / NBANDS;
    int b   = j % NBANDS;
    int band0 = b * BSTEP;
    int rows  = min(BROWS, H_ - band0);
    int words = rows * W_;

    // ---- stage band rows -> LDS (coalesced float4; stride-324 rows) ----
    const float* xb = x + (size_t)t * HW_ + band0 * W_;
    for (int wi = tid * 4; wi < words; wi += 1024) {
        float4 v = *reinterpret_cast<const float4*>(xb + wi);
        int row = wi / W_;
        int col = wi - row * W_;
        *reinterpret_cast<float4*>(&lds[row * RP + col]) = v;
    }
    // ---- stage padded weight table ----
    for (int wi = tid * 4; wi < LDSW_W; wi += 1024) {
        *reinterpret_cast<float4*>(&ldsw[wi]) =
            *reinterpret_cast<const float4*>(spat_pad + wi);
    }
    __syncthreads();

    int lane = tid & 63;
    int w_   = tid >> 6;
    int g    = lane >> 4;     // neuron-group 0..3
    int r    = lane & 15;     // window row handled by this lane

    int count = cnt[b];
    const int4* list = lists + b * N;

    for (int i = w_ * 4 + g; i < count; i += 16) {
        int4 d = list[i];                    // broadcast within group
        int ax = d.y + r * RP;
        int aw = d.z + r * WPR;
        float a = 0.0f;
#pragma unroll
        for (int q = 0; q < 4; ++q) {
            const float4 pv = *reinterpret_cast<const float4*>(&lds[ax + 4 * q]);
            const float4 wv = *reinterpret_cast<const float4*>(&ldsw[aw + 4 * q]);
            a = fmaf(pv.x, wv.x, a);
            a = fmaf(pv.y, wv.y, a);
            a = fmaf(pv.z, wv.z, a);
            a = fmaf(pv.w, wv.w, a);
        }
        a += __shfl_xor(a, 1, 64);
        a += __shfl_xor(a, 2, 64);
        a += __shfl_xor(a, 4, 64);
        a += __shfl_xor(a, 8, 64);
        if (r == 0) y[(size_t)d.x * T_ + t] = a;
    }
}

// ---------------------------------------------------------------------------
// Stage 2: out[n, t0] = ALPHA * softplus(BETA * (sum_k y[n,t0+k]*temporal[k]
//                                                 - GAMMA))
// ---------------------------------------------------------------------------
__global__ void stage2_kernel(const float* __restrict__ y,
                              const float* __restrict__ temporal,
                              float* __restrict__ out, int N)
{
    __shared__ float tw[K_];
    if (threadIdx.x < K_) tw[threadIdx.x] = temporal[threadIdx.x];
    __syncthreads();

    int n  = blockIdx.x;
    int t0 = threadIdx.x;
    if (n >= N || t0 >= NWIN) return;

    const float* yn = y + (size_t)n * T_;
    float g = 0.0f;
#pragma unroll
    for (int k = 0; k < K_; ++k)
        g = fmaf(yn[t0 + k], tw[k], g);

    float z = BETA * (g - GAMMA);
    float sp = fmaxf(z, 0.0f) + log1pf(expf(-fabsf(z)));
    out[n * NWIN + t0] = ALPHA * sp;
}

// ---------------------------------------------------------------------------
extern "C" void kernel_launch(void* const* d_in, const int* in_sizes, int n_in,
                              void* d_out, int out_size, void* d_ws, size_t ws_size,
                              hipStream_t stream)
{
    const float* x  = (const float*)d_in[0];  // (T, H, W) f32
    const float* w  = (const float*)d_in[1];  // (K*RF*RF,) f32
    const int*   rf = (const int*)d_in[2];    // (N, 256) i32

    int N = in_sizes[2] / (RF_ * RF_);

    // ws layout (4B units):
    // [0,256) spatial | [256,320) temporal | [320,384) cnt |
    // [384,1536) spat_pad | [1536, 1536+4*9N) lists(int4) | y: N*T
    float* spatial  = (float*)d_ws;
    float* temporal = spatial + 256;
    int*   cnt      = (int*)d_ws + 320;
    float* spat_pad = (float*)d_ws + 384;
    int4*  lists    = (int4*)((int*)d_ws + 1536);
    float* y        = (float*)d_ws + 1536 + 4 * NBANDS * N;

    prep_kernel<<<1, 1024, 0, stream>>>(w, rf, spatial, temporal, spat_pad,
                                        cnt, lists, N);
    stage1_kernel<<<T_ * NBANDS, 256, 0, stream>>>(x, spat_pad, cnt, lists, y, N);
    stage2_kernel<<<N, 384, 0, stream>>>(y, temporal, (float*)d_out, N);
}

// Round 7
// 57.945 us; speedup vs baseline: 2.5302x; 1.5509x over previous
//
#include <hip/hip_runtime.h>
#include <math.h>

constexpr int H_ = 180, W_ = 320, RF_ = 16, K_ = 20, T_ = 400;
constexpr int HW_ = H_ * W_;
constexpr int NWIN = T_ - K_ + 1;   // 381
constexpr int PW   = W_ + 2 * RF_;  // 352 (padded width used by rf_indices)
constexpr float ALPHA = 50.0f, BETA = 1.0f, GAMMA = 0.0f;
constexpr int NXCD = 8;
constexpr int T_PER_XCD = T_ / NXCD;   // 50 frames per XCD
constexpr int CH = 8;                  // frames per reduction chunk
constexpr int NCHUNK = (T_PER_XCD + CH - 1) / CH;   // 7 (last partial)

__device__ inline float wave_sum64(float v) {
#pragma unroll
    for (int off = 1; off < 64; off <<= 1)
        v += __shfl_xor(v, off, 64);
    return v;
}

// ---------------------------------------------------------------------------
// Kernel 0: factorize w (K x 256) into temporal[K] (x) spatial[256].
// w is an exact rank-1 outer product; LS-project onto the largest row.
// ---------------------------------------------------------------------------
__global__ void factorize_kernel(const float* __restrict__ w,
                                 float* __restrict__ spatial,   // 256
                                 float* __restrict__ temporal)  // K
{
    int l = threadIdx.x;  // 0..63
    float best = -1.0f;
    int k0 = 0;
    for (int k = 0; k < K_; ++k) {
        float s = 0.0f;
#pragma unroll
        for (int j = 0; j < 4; ++j) {
            float v = w[k * 256 + l + j * 64];
            s = fmaf(v, v, s);
        }
        s = wave_sum64(s);
        if (s > best) { best = s; k0 = k; }
    }
#pragma unroll
    for (int j = 0; j < 4; ++j)
        spatial[l + j * 64] = w[k0 * 256 + l + j * 64];
    float inv_s2 = 1.0f / best;
    for (int k = 0; k < K_; ++k) {
        float d = 0.0f;
#pragma unroll
        for (int j = 0; j < 4; ++j)
            d = fmaf(w[k * 256 + l + j * 64], w[k0 * 256 + l + j * 64], d);
        d = wave_sum64(d);
        if (l == 0) temporal[k] = d * inv_s2;
    }
}

// ---------------------------------------------------------------------------
// Kernel 1: y[n, t] = sum_p x_patch[t, n, p] * spatial[p]
//
// One wave per (neuron, 50-frame XCD range). Lane l loads ONE float4 per
// frame: window row lane>>2, column quad lane&3 -> full 256-px RF in one
// wave instruction (4 consecutive-lane quads = 64B per row). Window origin
// clamped in-frame; zero-pad semantics recovered by shifting/zeroing the
// per-lane weights (once per wave).
//
// SOFTWARE PIPELINE (the round-6 change): chunks of 8 frames double-buffered
// A/B — all 8 global_load_dwordx4 of chunk c+1 are issued BEFORE the
// FMA+reduce of chunk c, fully unrolled so buffer choice is compile-time.
// Hides the ~300cy L2 latency behind ~160cy of VALU per chunk.
// ---------------------------------------------------------------------------
__global__ __launch_bounds__(256) void stage1_kernel(
    const float* __restrict__ x, const int* __restrict__ rf,
    const float* __restrict__ spatial, float* __restrict__ y,
    int N)
{
    int lane = threadIdx.x & 63;
    int wid  = threadIdx.x >> 6;

    int b   = blockIdx.x;
    int xcd = b & (NXCD - 1);
    int nch = b >> 3;

    int n = nch * 4 + wid;
    if (n >= N) return;
    int t0 = xcd * T_PER_XCD;

    int base = rf[n * 256];          // = v*PW + h (first padded index)
    int r0 = base / PW - RF_;        // window origin in frame (may be <0)
    int c0 = base % PW - RF_;
    int r0c = min(max(r0, 0), H_ - RF_);   // clamped origin (loads in-bounds)
    int c0c = min(max(c0, 0), W_ - RF_);

    int lr = lane >> 2;              // window row 0..15
    int q  = lane & 3;               // column quad 0..3
    int off = (r0c + lr) * W_ + c0c + q * 4;

    // weights matched to the CLAMPED window; outside true RF -> 0 (zero-pad)
    float wv[4];
    int rr = lr + (r0c - r0);
#pragma unroll
    for (int j = 0; j < 4; ++j) {
        int cc = q * 4 + j + (c0c - c0);
        bool ok = (rr >= 0) & (rr < RF_) & (cc >= 0) & (cc < RF_);
        wv[j] = ok ? spatial[rr * RF_ + cc] : 0.0f;
    }

    const float* xp = x + (size_t)t0 * HW_ + off;   // per-lane base pointer
    float* yp = y + (size_t)n * T_ + t0;

    int fr_out = ((lane & 1) << 2) | (lane & 2) | ((lane & 4) >> 2); // bitrev3

#define LOADCH(buf, cbase, clampf)                                            \
    do {                                                                      \
        _Pragma("unroll")                                                     \
        for (int j = 0; j < CH; ++j) {                                        \
            int f = (cbase) + j;                                              \
            if (clampf) f = f < T_PER_XCD ? f : T_PER_XCD - 1;                \
            buf[j] = *reinterpret_cast<const float4*>(xp + (size_t)f * HW_);  \
        }                                                                     \
    } while (0)

#define REDSTORE(buf, cbase)                                                  \
    do {                                                                      \
        float acc[CH];                                                        \
        _Pragma("unroll")                                                     \
        for (int j = 0; j < CH; ++j) {                                        \
            float a = buf[j].x * wv[0];                                       \
            a = fmaf(buf[j].y, wv[1], a);                                     \
            a = fmaf(buf[j].z, wv[2], a);                                     \
            acc[j] = fmaf(buf[j].w, wv[3], a);                                \
        }                                                                     \
        _Pragma("unroll")                                                     \
        for (int s = 0; s < 3; ++s) {                                         \
            const int m = 1 << s;                                             \
            const int half = CH >> (s + 1);                                   \
            bool hi = (lane & m) != 0;                                        \
            float nv[CH / 2];                                                 \
            _Pragma("unroll")                                                 \
            for (int j = 0; j < half; ++j) {                                  \
                float keep = hi ? acc[half + j] : acc[j];                     \
                float send = hi ? acc[j] : acc[half + j];                     \
                nv[j] = keep + __shfl_xor(send, m, 64);                       \
            }                                                                 \
            _Pragma("unroll")                                                 \
            for (int j = 0; j < half; ++j) acc[j] = nv[j];                    \
        }                                                                     \
        float r = acc[0];                                                     \
        r += __shfl_xor(r, 8, 64);                                            \
        r += __shfl_xor(r, 16, 64);                                           \
        r += __shfl_xor(r, 32, 64);                                           \
        if (lane < 8 && (cbase) + fr_out < T_PER_XCD)                         \
            yp[(cbase) + fr_out] = r;                                         \
    } while (0)

    float4 bA[CH], bB[CH];
    LOADCH(bA, 0, false);
#pragma unroll
    for (int c = 0; c < NCHUNK; ++c) {
        if (c + 1 < NCHUNK) {
            if (c & 1) LOADCH(bA, (c + 1) * CH, (c + 1) == NCHUNK - 1);
            else       LOADCH(bB, (c + 1) * CH, (c + 1) == NCHUNK - 1);
        }
        if (c & 1) REDSTORE(bB, c * CH);
        else       REDSTORE(bA, c * CH);
    }
#undef LOADCH
#undef REDSTORE
}

// ---------------------------------------------------------------------------
// Kernel 2: out[n, t0] = ALPHA * softplus(BETA * (sum_k y[n,t0+k]*temporal[k]
//                                                  - GAMMA))
// ---------------------------------------------------------------------------
__global__ void stage2_kernel(const float* __restrict__ y,
                              const float* __restrict__ temporal,
                              float* __restrict__ out, int N)
{
    __shared__ float tw[K_];
    if (threadIdx.x < K_) tw[threadIdx.x] = temporal[threadIdx.x];
    __syncthreads();

    int n  = blockIdx.x;
    int t0 = threadIdx.x;
    if (n >= N || t0 >= NWIN) return;

    const float* yn = y + (size_t)n * T_;
    float g = 0.0f;
#pragma unroll
    for (int k = 0; k < K_; ++k)
        g = fmaf(yn[t0 + k], tw[k], g);

    float z = BETA * (g - GAMMA);
    float sp = fmaxf(z, 0.0f) + log1pf(expf(-fabsf(z)));
    out[n * NWIN + t0] = ALPHA * sp;
}

// ---------------------------------------------------------------------------
extern "C" void kernel_launch(void* const* d_in, const int* in_sizes, int n_in,
                              void* d_out, int out_size, void* d_ws, size_t ws_size,
                              hipStream_t stream)
{
    const float* x  = (const float*)d_in[0];  // (T, H, W) f32
    const float* w  = (const float*)d_in[1];  // (K*RF*RF,) f32
    const int*   rf = (const int*)d_in[2];    // (N, 256) i32

    int N   = in_sizes[2] / (RF_ * RF_);
    int NCH = (N + 3) / 4;                    // 4 neurons (waves) per block

    float* spatial  = (float*)d_ws;           // 256
    float* temporal = spatial + 256;          // 20 (pad to 512)
    float* y        = spatial + 512;          // N * T

    factorize_kernel<<<1, 64, 0, stream>>>(w, spatial, temporal);
    stage1_kernel<<<NXCD * NCH, 256, 0, stream>>>(x, rf, spatial, y, N);
    stage2_kernel<<<N, 384, 0, stream>>>(y, temporal, (float*)d_out, N);
}